// Round 6
// baseline (238.730 us; speedup 1.0000x reference)
//
#include <hip/hip_runtime.h>
#include <hip/hip_bf16.h>
#include <math.h>

#define NB 4
#define NL 256
#define ND 512
#define NH 8
#define NR 64
#define NDK 64

typedef float f32x4 __attribute__((ext_vector_type(4)));
typedef short s16x8 __attribute__((ext_vector_type(8)));
typedef unsigned short u16;
typedef u16 u16x4 __attribute__((ext_vector_type(4)));
typedef unsigned int u32;
typedef u32 u32x2 __attribute__((ext_vector_type(2)));
typedef u32 u32x4 __attribute__((ext_vector_type(4)));

static __device__ __forceinline__ u16 f2bf(float f) {
    __hip_bfloat16 h = __float2bfloat16(f);   // RNE
    return __builtin_bit_cast(unsigned short, h);
}
// packed bf16 pair -> two f32 (lo = bits<<16, hi = bits&0xffff0000)
static __device__ __forceinline__ float bflo(u32 u) {
    return __builtin_bit_cast(float, u << 16);
}
static __device__ __forceinline__ float bfhi(u32 u) {
    return __builtin_bit_cast(float, u & 0xffff0000u);
}

// ---------------------------------------------------------------------------
// Kernel A: convert inputs + weights f32 -> bf16.
// jobs: 0 query, 1 key, 2 value (524288 ea); 3 Wq, 4 Wk, 5 Wv, 6 Wo (262144).
// ---------------------------------------------------------------------------
__global__ __launch_bounds__(256)
void convert_bf16_kernel(const float* __restrict__ q, const float* __restrict__ k,
                         const float* __restrict__ v, const float* __restrict__ wq,
                         const float* __restrict__ wk, const float* __restrict__ wv,
                         const float* __restrict__ wo,
                         u16* __restrict__ oq, u16* __restrict__ ok, u16* __restrict__ ov,
                         u16* __restrict__ owq, u16* __restrict__ owk,
                         u16* __restrict__ owv, u16* __restrict__ owo)
{
    const int job = blockIdx.y;
    const float* src; u16* dst; int n;
    switch (job) {
        case 0: src = q;  dst = oq;  n = 524288; break;
        case 1: src = k;  dst = ok;  n = 524288; break;
        case 2: src = v;  dst = ov;  n = 524288; break;
        case 3: src = wq; dst = owq; n = 262144; break;
        case 4: src = wk; dst = owk; n = 262144; break;
        case 5: src = wv; dst = owv; n = 262144; break;
        default: src = wo; dst = owo; n = 262144; break;
    }
    int idx = (blockIdx.x * 256 + threadIdx.x) * 4;
    if (idx >= n) return;
    f32x4 x = *(const f32x4*)&src[idx];
    u16x4 o;
    o.x = f2bf(x.x); o.y = f2bf(x.y); o.z = f2bf(x.z); o.w = f2bf(x.w);
    *(u16x4*)&dst[idx] = o;
}

// ---------------------------------------------------------------------------
// Kernel B: W-prep (f32 compute, bf16 out).
//  z=0: W3[h*64+r][e] = sum_d rel_k[h,r,d] * Wq[h*64+d][e]   (for c2p)
//  z=1: W2[h*64+r][e] = sum_d rel_q[h,r,d] * Wk[h*64+d][e]   (for p2c)
//  z=2 (blocks 0,1): b3[hr] = rel_k[h,r,:].bq_head ; b2 from rel_q,bk (f32)
// ---------------------------------------------------------------------------
__global__ __launch_bounds__(256)
void wprep_kernel(const float* __restrict__ Wq, const float* __restrict__ bq,
                  const float* __restrict__ Wk, const float* __restrict__ bk,
                  const float* __restrict__ RelK, const float* __restrict__ RelQ,
                  u16* __restrict__ W3, float* __restrict__ b3,
                  u16* __restrict__ W2, float* __restrict__ b2)
{
    const int z = blockIdx.y;
    const int t = threadIdx.x;

    if (z == 2) {
        if (blockIdx.x >= 2) return;
        const float* rel  = blockIdx.x ? RelQ : RelK;
        const float* bias = blockIdx.x ? bk : bq;
        float* out        = blockIdx.x ? b2 : b3;
        for (int hr = t; hr < 512; hr += 256) {
            int h = hr >> 6, r = hr & 63;
            float s = 0.f;
            #pragma unroll 8
            for (int d = 0; d < 64; ++d)
                s += rel[((size_t)h * NR + r) * NDK + d] * bias[h * 64 + d];
            out[hr] = s;
        }
        return;
    }

    const float* rel = z ? RelQ : RelK;   // [8][64][64]
    const float* W   = z ? Wk : Wq;       // [512][512]
    u16* Wout        = z ? W2 : W3;

    const int h  = blockIdx.x >> 3;
    const int e0 = (blockIdx.x & 7) * 64;

    __shared__ float At[64][68];   // At[d][r]
    __shared__ float Bs[64][68];   // Bs[d][e]

    const int ty = t >> 4, tx = t & 15;

    #pragma unroll
    for (int pass = 0; pass < 4; ++pass) {
        {
            int lr = t >> 2, lk = (t & 3) << 2;
            f32x4 a = *(const f32x4*)&rel[((size_t)h * NR + lr) * NDK + pass * 16 + lk];
            At[pass*16 + lk + 0][lr] = a.x; At[pass*16 + lk + 1][lr] = a.y;
            At[pass*16 + lk + 2][lr] = a.z; At[pass*16 + lk + 3][lr] = a.w;
        }
        {
            int dr = t >> 4, ec = (t & 15) << 2;
            *(f32x4*)&Bs[pass*16 + dr][ec] =
                *(const f32x4*)&W[(size_t)(h*64 + pass*16 + dr) * ND + e0 + ec];
        }
    }
    __syncthreads();

    float acc[4][4] = {{0.f,0.f,0.f,0.f},{0.f,0.f,0.f,0.f},
                       {0.f,0.f,0.f,0.f},{0.f,0.f,0.f,0.f}};
    #pragma unroll 16
    for (int kk = 0; kk < 64; ++kk) {
        f32x4 a4 = *(const f32x4*)&At[kk][ty*4];
        f32x4 b4 = *(const f32x4*)&Bs[kk][tx*4];
        #pragma unroll
        for (int i = 0; i < 4; ++i) {
            acc[i][0] += a4[i]*b4.x; acc[i][1] += a4[i]*b4.y;
            acc[i][2] += a4[i]*b4.z; acc[i][3] += a4[i]*b4.w;
        }
    }

    #pragma unroll
    for (int i = 0; i < 4; ++i) {
        u16x4 o;
        o.x = f2bf(acc[i][0]); o.y = f2bf(acc[i][1]);
        o.z = f2bf(acc[i][2]); o.w = f2bf(acc[i][3]);
        *(u16x4*)&Wout[(size_t)(h*64 + ty*4 + i) * ND + e0 + tx*4] = o;
    }
}

// ---------------------------------------------------------------------------
// Kernel C: batched projection via MFMA (no LDS).  Out = X @ W^T + bias.
//  z=0 q->bf16 [B,H,L,64], z=1 k->bf16 [B,H,L,64], z=2 v->bf16 [B,H,L,64],
//  z=3 c2p->f32 [B,H,L,64], z=4 p2c->bf16 TRANSPOSED [B, m, r, 8h].
// Block = 64 rows x 64 cols (one head); 4 waves, wave w = rows w*16..+16.
// ---------------------------------------------------------------------------
__global__ __launch_bounds__(256)
void gemm5_mfma_kernel(const u16* __restrict__ xq, const u16* __restrict__ xk,
                       const u16* __restrict__ xv,
                       const u16* __restrict__ wq, const u16* __restrict__ wk,
                       const u16* __restrict__ wv, const u16* __restrict__ w3,
                       const u16* __restrict__ w2,
                       const float* __restrict__ bq, const float* __restrict__ bk,
                       const float* __restrict__ bv, const float* __restrict__ b3,
                       const float* __restrict__ b2,
                       u16* __restrict__ qbf, u16* __restrict__ kbf,
                       u16* __restrict__ vbf, float* __restrict__ c2p,
                       u16* __restrict__ p2ct)
{
    const int z = blockIdx.z;
    const u16* __restrict__ X = (z==0 || z==3) ? xq : ((z==1 || z==4) ? xk : xv);
    const u16* __restrict__ W = (z==0)?wq:(z==1)?wk:(z==2)?wv:(z==3)?w3:w2;
    const float* __restrict__ bias = (z==0)?bq:(z==1)?bk:(z==2)?bv:(z==3)?b3:b2;

    const int t    = threadIdx.x;
    const int wv_  = t >> 6;
    const int lane = t & 63;
    const int lr   = lane & 15;
    const int kg   = lane >> 4;

    const int m0 = blockIdx.x * 64 + wv_ * 16;
    const int h  = blockIdx.y;
    const int n0 = h * 64;

    const u16* Ap = X + (size_t)(m0 + lr) * ND + kg * 8;
    const u16* Bp = W + (size_t)(n0 + lr) * ND + kg * 8;

    f32x4 acc[4] = {{0,0,0,0},{0,0,0,0},{0,0,0,0},{0,0,0,0}};

    for (int kt = 0; kt < 16; ++kt) {
        s16x8 a = *(const s16x8*)(Ap + kt * 32);
        #pragma unroll
        for (int nt = 0; nt < 4; ++nt) {
            s16x8 b = *(const s16x8*)(Bp + (size_t)nt * 16 * ND + kt * 32);
            acc[nt] = __builtin_amdgcn_mfma_f32_16x16x32_bf16(a, b, acc[nt], 0, 0, 0);
        }
    }

    #pragma unroll
    for (int nt = 0; nt < 4; ++nt) {
        const int col = n0 + nt * 16 + lr;
        const float bb = bias[col];
        #pragma unroll
        for (int r = 0; r < 4; ++r) {
            int row = m0 + kg * 4 + r;
            int bI  = row >> 8;
            int lI  = row & 255;
            float val = acc[nt][r] + bb;
            if (z == 4) {
                // p2c transposed: [b, m=lI, r=nt*16+lr, h]
                p2ct[(((size_t)(bI * NL + lI)) * 64 + nt * 16 + lr) * 8 + h] = f2bf(val);
            } else {
                size_t oidx = (((size_t)(bI * NH + h)) * NL + lI) * 64 + nt * 16 + lr;
                if      (z == 0) qbf[oidx] = f2bf(val);
                else if (z == 1) kbf[oidx] = f2bf(val);
                else if (z == 2) vbf[oidx] = f2bf(val);
                else             c2p[oidx] = val;
            }
        }
    }
}

// ---------------------------------------------------------------------------
// Kernel D (FUSED, all-heads): per block = (b, 2 l-rows, all 8 heads).
// 512 threads (8 waves), grid 512 = 2 blocks/CU.  XCD-bijective swizzle:
// bid&7 = xcd, b = xcd>>1 -> K[b]+V[b]+p2ct[b] (3 MB bf16) L2-resident.
//  Stage:  q rows (f32), c2p rows, rel_pos rows, mask row.
//  A: QK^T VALU dots (thread = (h, 4 m-rows), 2 l each; K rows read once).
//  B: gathers (p2ct 8B/4h, c2p LDS) + scale + mask.
//  C: softmax, 16 (l,h)-rows x 32 lanes.
//  D: stream rel_v[b,l,m,0:512] CONTIGUOUS 2048B rows (nontemporal) fused
//     with p@V (bf16 V from L2); ctx written bf16.
// ---------------------------------------------------------------------------
__global__ __launch_bounds__(512, 4)
void attn_fused_kernel(const u16* __restrict__ qbf, const u16* __restrict__ kbf,
                       const u16* __restrict__ vbf,
                       const float* __restrict__ C2P, const u16* __restrict__ p2ct,
                       const int* __restrict__ RelPos, const void* __restrict__ MaskP,
                       const float* __restrict__ RV, u16* __restrict__ CTXB)
{
    const int bid  = blockIdx.x;
    const int xcd  = bid & 7;
    const int slot = bid >> 3;            // 0..63
    const int b    = xcd >> 1;
    const int l0   = (xcd & 1) * 128 + slot * 2;
    const int t    = threadIdx.x;

    __shared__ float sc[2][8][256];   // scores -> p  (16 KB)
    __shared__ float qs[2][8][64];    // q rows f32   (4 KB)
    __shared__ float cs[2][8][64];    // c2p rows     (4 KB)
    __shared__ int   rp_lds[2][256];  // rel_pos      (2 KB)
    __shared__ float maskv[256];      // mask row     (1 KB)
    __shared__ f32x4 redv[2][128];    // phase-D reduce (4 KB)

    // ---- detect mask buffer layout (bool-u8 / f32 / i32), deterministic ----
    const unsigned char* mu = (const unsigned char*)MaskP;
    int loc1 = 0, loc23 = 0;
    if (t < 250) {
        loc1  = mu[t*4 + 1];
        loc23 = mu[t*4 + 2] | mu[t*4 + 3];
    }
    int any1  = __syncthreads_or(loc1);
    int any23 = __syncthreads_or(loc23);
    const int mlayout = any1 ? 0 : (any23 ? 1 : 2);  // 0=u8, 1=f32, 2=i32

    // ---- stage: q (bf16->f32), c2p, rel_pos, mask ----
    if (t < 256) {
        // q: 1024 elems as 256 x u16x4; hl = t>>4 (l*8+h), d4 = t&15
        int l = t >> 7, h = (t >> 4) & 7, d4 = t & 15;
        u32x2 qw = *(const u32x2*)&qbf[(((size_t)(b*NH + h)) * NL + l0 + l) * 64 + d4*4];
        qs[l][h][d4*4+0] = bflo(qw.x); qs[l][h][d4*4+1] = bfhi(qw.x);
        qs[l][h][d4*4+2] = bflo(qw.y); qs[l][h][d4*4+3] = bfhi(qw.y);
        // c2p: 1024 f32 as 256 x f32x4
        *(f32x4*)&cs[l][h][d4*4] =
            *(const f32x4*)&C2P[(((size_t)(b*NH + h)) * NL + l0 + l) * 64 + d4*4];
        // mask row
        float mval;
        if (mlayout == 0)      mval = (float)mu[b * NL + t];
        else if (mlayout == 1) mval = ((const float*)MaskP)[b * NL + t];
        else                   mval = (float)((const int*)MaskP)[b * NL + t];
        maskv[t] = mval;
    } else {
        int tt = t - 256;
        if (tt < 128) {   // rel_pos: 512 ints as 128 x int4
            int l = tt >> 6, m4 = tt & 63;
            *(int4*)&rp_lds[l][m4*4] =
                *(const int4*)&RelPos[((size_t)b * NL + l0 + l) * NL + m4*4];
        }
    }
    __syncthreads();

    // ---- Phase A: QK^T dots.  thread: h = t>>6, 4 m-rows, 2 l ----
    {
        const int h  = t >> 6;
        const int m0 = (t & 63) * 4;
        float acc[2][4] = {{0.f,0.f,0.f,0.f},{0.f,0.f,0.f,0.f}};
        const u16* kr = kbf + (((size_t)(b*NH + h)) * NL + m0) * 64;
        for (int c = 0; c < 8; ++c) {
            f32x4 q00 = *(const f32x4*)&qs[0][h][c*8];
            f32x4 q01 = *(const f32x4*)&qs[0][h][c*8+4];
            f32x4 q10 = *(const f32x4*)&qs[1][h][c*8];
            f32x4 q11 = *(const f32x4*)&qs[1][h][c*8+4];
            #pragma unroll
            for (int i = 0; i < 4; ++i) {
                u32x4 kw = *(const u32x4*)(kr + (size_t)i * 64 + c * 8);
                float f0 = bflo(kw.x), f1 = bfhi(kw.x);
                float f2 = bflo(kw.y), f3 = bfhi(kw.y);
                float f4 = bflo(kw.z), f5 = bfhi(kw.z);
                float f6 = bflo(kw.w), f7 = bfhi(kw.w);
                acc[0][i] += f0*q00.x + f1*q00.y + f2*q00.z + f3*q00.w
                           + f4*q01.x + f5*q01.y + f6*q01.z + f7*q01.w;
                acc[1][i] += f0*q10.x + f1*q10.y + f2*q10.z + f3*q10.w
                           + f4*q11.x + f5*q11.y + f6*q11.z + f7*q11.w;
            }
        }
        f32x4 w0; w0.x = acc[0][0]; w0.y = acc[0][1]; w0.z = acc[0][2]; w0.w = acc[0][3];
        f32x4 w1; w1.x = acc[1][0]; w1.y = acc[1][1]; w1.z = acc[1][2]; w1.w = acc[1][3];
        *(f32x4*)&sc[0][h][m0] = w0;
        *(f32x4*)&sc[1][h][m0] = w1;
    }
    __syncthreads();

    // ---- Phase B: gathers + scale + mask.  thread: m = t&255, hs = (t>>8)*4 ----
    {
        const int m  = t & 255;
        const int hs = (t >> 8) * 4;
        const float msk = maskv[m];
        #pragma unroll
        for (int l = 0; l < 2; ++l) {
            int r = rp_lds[l][m];
            u32x2 pw = *(const u32x2*)&p2ct[(((size_t)(b * NL + m)) * 64 + r) * 8 + hs];
            float pv[4] = {bflo(pw.x), bfhi(pw.x), bflo(pw.y), bfhi(pw.y)};
            #pragma unroll
            for (int j = 0; j < 4; ++j) {
                int hh = hs + j;
                float s = sc[l][hh][m] + cs[l][hh][r] + pv[j];
                s *= (1.0f / 24.0f);   // 1 / (3 * sqrt(64))
                if (msk != 0.0f) s = -1e9f;
                sc[l][hh][m] = s;
            }
        }
    }
    __syncthreads();

    // ---- Phase C: softmax.  row = t>>5 (l = row>>3, h = row&7), 32 lanes ----
    {
        const int row = t >> 5;
        const int l   = row >> 3;
        const int h   = row & 7;
        const int jj  = t & 31;
        float mx = -INFINITY;
        #pragma unroll
        for (int s32 = 0; s32 < 8; ++s32) mx = fmaxf(mx, sc[l][h][jj + 32*s32]);
        #pragma unroll
        for (int off = 16; off >= 1; off >>= 1) mx = fmaxf(mx, __shfl_xor(mx, off, 32));

        float sum = 0.f;
        float ev[8];
        #pragma unroll
        for (int s32 = 0; s32 < 8; ++s32) {
            ev[s32] = __expf(sc[l][h][jj + 32*s32] - mx);
            sum += ev[s32];
        }
        #pragma unroll
        for (int off = 16; off >= 1; off >>= 1) sum += __shfl_xor(sum, off, 32);
        float inv = 1.0f / sum;
        #pragma unroll
        for (int s32 = 0; s32 < 8; ++s32) sc[l][h][jj + 32*s32] = ev[s32] * inv;
    }
    __syncthreads();

    // ---- Phase D: stream rel_v full rows + p@V ----
    {
        const int lgrp = t >> 8;          // which l-row
        const int half = (t >> 7) & 1;    // m parity
        const int d4   = t & 127;         // f32x4 column 0..127
        const int hD   = d4 >> 4;
        const int dk4  = d4 & 15;

        const float* rvp = RV + ((size_t)(b * NL + l0 + lgrp) * NL) * ND + d4 * 4;
        const u16*   vvp = vbf + ((size_t)(b * NH + hD) * NL) * 64 + dk4 * 4;

        f32x4 acc = {0.f, 0.f, 0.f, 0.f};
        #pragma unroll 4
        for (int m = half; m < NL; m += 2) {
            float w = sc[lgrp][hD][m];
            f32x4 rv = __builtin_nontemporal_load((const f32x4*)(rvp + (size_t)m * ND));
            u32x2 vw = *(const u32x2*)(vvp + (size_t)m * 64);
            f32x4 vv;
            vv.x = bflo(vw.x); vv.y = bfhi(vw.x); vv.z = bflo(vw.y); vv.w = bfhi(vw.y);
            acc += w * (rv + vv);
        }

        if (half) redv[lgrp][d4] = acc;
        __syncthreads();
        if (!half) {
            acc += redv[lgrp][d4];
            u16x4 o;
            o.x = f2bf(acc.x); o.y = f2bf(acc.y); o.z = f2bf(acc.z); o.w = f2bf(acc.w);
            *(u16x4*)&CTXB[((size_t)(b * NL + l0 + lgrp)) * ND + d4 * 4] = o;
        }
    }
}

// ---------------------------------------------------------------------------
// Kernel E: out = ctx @ Wo^T + bo via MFMA.  32x64 tiles, grid (32,8)=256.
// wave w: rows (w&1)*16, cols (w>>1)*32.
// ---------------------------------------------------------------------------
__global__ __launch_bounds__(256)
void out_proj_mfma_kernel(const u16* __restrict__ A, const u16* __restrict__ W,
                          const float* __restrict__ bias, float* __restrict__ C)
{
    const int t    = threadIdx.x;
    const int wv_  = t >> 6;
    const int lane = t & 63;
    const int lr   = lane & 15;
    const int kg   = lane >> 4;

    const int m0 = blockIdx.x * 32 + (wv_ & 1) * 16;
    const int n0 = blockIdx.y * 64 + (wv_ >> 1) * 32;

    const u16* Ap = A + (size_t)(m0 + lr) * ND + kg * 8;
    const u16* Bp = W + (size_t)(n0 + lr) * ND + kg * 8;

    f32x4 acc[2] = {{0,0,0,0},{0,0,0,0}};

    for (int kt = 0; kt < 16; ++kt) {
        s16x8 a = *(const s16x8*)(Ap + kt * 32);
        #pragma unroll
        for (int nt = 0; nt < 2; ++nt) {
            s16x8 b = *(const s16x8*)(Bp + (size_t)nt * 16 * ND + kt * 32);
            acc[nt] = __builtin_amdgcn_mfma_f32_16x16x32_bf16(a, b, acc[nt], 0, 0, 0);
        }
    }

    #pragma unroll
    for (int nt = 0; nt < 2; ++nt) {
        const int col = n0 + nt * 16 + lr;
        const float bb = bias[col];
        #pragma unroll
        for (int r = 0; r < 4; ++r) {
            int row = m0 + kg * 4 + r;
            C[(size_t)row * ND + col] = acc[nt][r] + bb;
        }
    }
}

// ---------------------------------------------------------------------------
extern "C" void kernel_launch(void* const* d_in, const int* in_sizes, int n_in,
                              void* d_out, int out_size, void* d_ws, size_t ws_size,
                              hipStream_t stream)
{
    const float* query   = (const float*)d_in[0];
    const float* key     = (const float*)d_in[1];
    const float* value   = (const float*)d_in[2];
    const void*  mask    = d_in[3];
    const int*   rel_pos = (const int*)d_in[4];
    const float* rel_q   = (const float*)d_in[5];
    const float* rel_k   = (const float*)d_in[6];
    const float* rel_v   = (const float*)d_in[7];
    const float* Wq = (const float*)d_in[8];
    const float* bq = (const float*)d_in[9];
    const float* Wk = (const float*)d_in[10];
    const float* bk = (const float*)d_in[11];
    const float* Wv = (const float*)d_in[12];
    const float* bv = (const float*)d_in[13];
    const float* Wo = (const float*)d_in[14];
    const float* bo = (const float*)d_in[15];

    // ---- workspace layout ----
    float* wsf  = (float*)d_ws;
    float* c2p  = wsf;                    // 524288 f32 [B,H,L,64]
    float* b3   = c2p + 524288;           // 512 f32
    float* b2   = b3 + 512;               // 512 f32
    u16* wsu  = (u16*)(b2 + 512);
    u16* xqb  = wsu;                      // 524288 u16
    u16* xkb  = xqb + 524288;
    u16* xvb  = xkb + 524288;
    u16* wqb  = xvb + 524288;             // 262144 u16
    u16* wkb  = wqb + 262144;
    u16* wvb  = wkb + 262144;
    u16* wob  = wvb + 262144;
    u16* w3b  = wob + 262144;
    u16* w2b  = w3b + 262144;
    u16* qbf  = w2b + 262144;             // 524288 u16
    u16* kbf  = qbf + 524288;
    u16* vbf  = kbf + 524288;
    u16* p2ct = vbf + 524288;             // 524288 u16 [B, m, r, 8h]
    u16* ctxb = p2ct + 524288;            // 524288 u16

    convert_bf16_kernel<<<dim3(512, 7), 256, 0, stream>>>(
        query, key, value, Wq, Wk, Wv, Wo, xqb, xkb, xvb, wqb, wkb, wvb, wob);

    wprep_kernel<<<dim3(64, 3), 256, 0, stream>>>(
        Wq, bq, Wk, bk, rel_k, rel_q, w3b, b3, w2b, b2);

    gemm5_mfma_kernel<<<dim3(16, 8, 5), 256, 0, stream>>>(
        xqb, xkb, xvb, wqb, wkb, wvb, w3b, w2b,
        bq, bk, bv, b3, b2, qbf, kbf, vbf, c2p, p2ct);

    attn_fused_kernel<<<dim3(512), 512, 0, stream>>>(
        qbf, kbf, vbf, c2p, p2ct, rel_pos, mask, rel_v, ctxb);

    out_proj_mfma_kernel<<<dim3(32, 8), 256, 0, stream>>>(ctxb, wob, bo, (float*)d_out);
}

// Round 7
// 185.284 us; speedup vs baseline: 1.2885x; 1.2885x over previous
//
#include <hip/hip_runtime.h>
#include <hip/hip_bf16.h>
#include <math.h>

#define NB 4
#define NL 256
#define ND 512
#define NH 8
#define NR 64
#define NDK 64

typedef float f32x4 __attribute__((ext_vector_type(4)));
typedef short s16x8 __attribute__((ext_vector_type(8)));
typedef unsigned short u16;
typedef u16 u16x4 __attribute__((ext_vector_type(4)));
typedef u16 u16x8 __attribute__((ext_vector_type(8)));
typedef unsigned int u32;

static __device__ __forceinline__ u16 f2bf(float f) {
    __hip_bfloat16 h = __float2bfloat16(f);   // RNE
    return __builtin_bit_cast(unsigned short, h);
}
static __device__ __forceinline__ float bf2f(u16 u) {
    return __builtin_bit_cast(float, (u32)u << 16);
}
// load 8 consecutive f32 and convert to a bf16 MFMA fragment
static __device__ __forceinline__ s16x8 loadcvt8(const float* __restrict__ p) {
    f32x4 lo = *(const f32x4*)p;
    f32x4 hi = *(const f32x4*)(p + 4);
    s16x8 r;
    r[0] = (short)f2bf(lo.x); r[1] = (short)f2bf(lo.y);
    r[2] = (short)f2bf(lo.z); r[3] = (short)f2bf(lo.w);
    r[4] = (short)f2bf(hi.x); r[5] = (short)f2bf(hi.y);
    r[6] = (short)f2bf(hi.z); r[7] = (short)f2bf(hi.w);
    return r;
}

// ---------------------------------------------------------------------------
// Kernel 1: q/k/v projection via MFMA, f32 inputs/weights cvt'd on the fly.
//  z=0 q->bf16 [B,H,L,64], z=1 k->bf16, z=2 v->f32.
// Block = 32 rows x 64 cols, 256 thr (4 waves: wave = (row-half, col-half)).
// Grid (32, 8, 3) = 768 blocks = 3/CU.
// D layout (m89-verified): row=(lane>>4)*4+reg, col=lane&15.
// ---------------------------------------------------------------------------
__global__ __launch_bounds__(256)
void gemm3_mfma_kernel(const float* __restrict__ Xq, const float* __restrict__ Xk,
                       const float* __restrict__ Xv,
                       const float* __restrict__ Wq, const float* __restrict__ bq,
                       const float* __restrict__ Wk, const float* __restrict__ bk,
                       const float* __restrict__ Wv, const float* __restrict__ bv,
                       u16* __restrict__ qbf, u16* __restrict__ kbf,
                       float* __restrict__ vws)
{
    const int z = blockIdx.z;
    const float* __restrict__ X    = (z == 0) ? Xq : ((z == 1) ? Xk : Xv);
    const float* __restrict__ W    = (z == 0) ? Wq : ((z == 1) ? Wk : Wv);
    const float* __restrict__ bias = (z == 0) ? bq : ((z == 1) ? bk : bv);

    const int t    = threadIdx.x;
    const int wv_  = t >> 6;
    const int lane = t & 63;
    const int lr   = lane & 15;
    const int kg   = lane >> 4;

    const int h  = blockIdx.y;
    const int m0 = blockIdx.x * 32 + (wv_ & 1) * 16;
    const int c0 = (wv_ >> 1) * 32;          // within-head col offset (0 or 32)

    const float* Ap = X + (size_t)(m0 + lr) * ND + kg * 8;
    const float* Bp = W + (size_t)(h * 64 + c0 + lr) * ND + kg * 8;

    f32x4 acc[2] = {{0,0,0,0},{0,0,0,0}};

    for (int kt = 0; kt < 16; ++kt) {
        s16x8 a = loadcvt8(Ap + kt * 32);
        #pragma unroll
        for (int nt = 0; nt < 2; ++nt) {
            s16x8 b = loadcvt8(Bp + (size_t)nt * 16 * ND + kt * 32);
            acc[nt] = __builtin_amdgcn_mfma_f32_16x16x32_bf16(a, b, acc[nt], 0, 0, 0);
        }
    }

    #pragma unroll
    for (int nt = 0; nt < 2; ++nt) {
        const int off = c0 + nt * 16 + lr;          // within-head col
        const float bb = bias[h * 64 + off];
        #pragma unroll
        for (int r = 0; r < 4; ++r) {
            int row = m0 + kg * 4 + r;
            int bI  = row >> 8;
            int lI  = row & 255;
            size_t oidx = (((size_t)(bI * NH + h)) * NL + lI) * 64 + off;
            float val = acc[nt][r] + bb;
            if      (z == 0) qbf[oidx] = f2bf(val);
            else if (z == 1) kbf[oidx] = f2bf(val);
            else             vws[oidx] = val;
        }
    }
}

// ---------------------------------------------------------------------------
// Kernel 2 (FUSED): per block = (bh, 16 l-rows), 512 thr (8 waves), grid 512.
// XCD swizzle: xcd=bid&7 -> b=xcd>>1, so kbf[b]+vws[b]+rel data L2-resident.
//  Prologue (MFMA, 1 barrier):
//    QK^T   -> sc[16][256]      (wave w: m-stripe w*32, 2 tiles)
//    c2p    -> cs[16][64]       (q . rel_k^T; waves 0-3, on-the-fly cvt)
//    p2c    -> psall[256][64]   (k . rel_q^T, bf16 in LDS; all waves, 2 m-tiles)
//  Phase B (no barriers): thread (i,jj): 8 m's: gather cs[i][r] + psall[m][r],
//    scale 1/24, mask -> sc.
//  Phase C (no barriers): row softmax, 32 lanes/row, p -> sc.   [barrier]
//  Phase D: stream rel_v[b,l,:,h*64..+64] (nontemporal, read-once) + p@V,
//    ctx written bf16.
// ---------------------------------------------------------------------------
__global__ __launch_bounds__(512, 4)
void attn_fused_kernel(const u16* __restrict__ qbf, const u16* __restrict__ kbf,
                       const float* __restrict__ vws,
                       const float* __restrict__ RelK, const float* __restrict__ RelQ,
                       const int* __restrict__ RelPos, const void* __restrict__ MaskP,
                       const float* __restrict__ RV, u16* __restrict__ CTXB)
{
    const int bid  = blockIdx.x;
    const int xcd  = bid & 7;
    const int idx  = bid >> 3;           // 0..63
    const int b    = xcd >> 1;
    const int lhalf= xcd & 1;
    const int h    = idx & 7;
    const int lt   = idx >> 3;           // 0..7
    const int l0   = lhalf * 128 + lt * 16;
    const int bh   = b * NH + h;
    const int t    = threadIdx.x;

    __shared__ float sc[16][257];     // scores -> p   (16.4 KB)
    __shared__ float cs[16][64];      // c2p           (4 KB)
    __shared__ u16   psall[256][64];  // p2c bf16      (32 KB)
    __shared__ float maskv[256];      // mask row      (1 KB)
    __shared__ f32x4 redv[256];       // phase-D reduce (4 KB)

    // ---- detect mask buffer layout (bool-u8 / f32 / i32), deterministic ----
    const unsigned char* mu = (const unsigned char*)MaskP;
    int loc1 = 0, loc23 = 0;
    if (t < 250) {
        loc1  = mu[t*4 + 1];
        loc23 = mu[t*4 + 2] | mu[t*4 + 3];
    }
    int any1  = __syncthreads_or(loc1);
    int any23 = __syncthreads_or(loc23);
    const int mlayout = any1 ? 0 : (any23 ? 1 : 2);  // 0=u8, 1=f32, 2=i32

    if (t < 256) {
        float mval;
        if (mlayout == 0)      mval = (float)mu[b * NL + t];
        else if (mlayout == 1) mval = ((const float*)MaskP)[b * NL + t];
        else                   mval = (float)((const int*)MaskP)[b * NL + t];
        maskv[t] = mval;
    }

    // ---- Prologue MFMAs ----
    {
        const int wv_  = t >> 6;
        const int lane = t & 63;
        const int lr   = lane & 15;
        const int kg   = lane >> 4;

        // A-frags: q rows of this l-tile
        const u16* Ap = qbf + ((size_t)bh * NL + l0 + lr) * 64 + kg * 8;
        s16x8 a0 = *(const s16x8*)Ap;
        s16x8 a1 = *(const s16x8*)(Ap + 32);

        // QK^T: wave's two 16-col m-tiles
        #pragma unroll
        for (int c = 0; c < 2; ++c) {
            int m0 = wv_ * 32 + c * 16;
            const u16* Bp = kbf + ((size_t)bh * NL + m0 + lr) * 64 + kg * 8;
            s16x8 b0 = *(const s16x8*)Bp;
            s16x8 b1 = *(const s16x8*)(Bp + 32);
            f32x4 acc = {0.f, 0.f, 0.f, 0.f};
            acc = __builtin_amdgcn_mfma_f32_16x16x32_bf16(a0, b0, acc, 0, 0, 0);
            acc = __builtin_amdgcn_mfma_f32_16x16x32_bf16(a1, b1, acc, 0, 0, 0);
            #pragma unroll
            for (int r = 0; r < 4; ++r)
                sc[kg * 4 + r][m0 + lr] = acc[r];
        }

        // c2p: waves 0..3, r-tile rt = wv_  (B = rel_k[h], f32 cvt)
        if (wv_ < 4) {
            const int rt = wv_;
            const float* Rp = RelK + ((size_t)h * NR + rt * 16 + lr) * NDK + kg * 8;
            s16x8 rb0 = loadcvt8(Rp);
            s16x8 rb1 = loadcvt8(Rp + 32);
            f32x4 acc = {0.f, 0.f, 0.f, 0.f};
            acc = __builtin_amdgcn_mfma_f32_16x16x32_bf16(a0, rb0, acc, 0, 0, 0);
            acc = __builtin_amdgcn_mfma_f32_16x16x32_bf16(a1, rb1, acc, 0, 0, 0);
            #pragma unroll
            for (int r = 0; r < 4; ++r)
                cs[kg * 4 + r][rt * 16 + lr] = acc[r];
        }

        // p2c: all waves, m-tiles {wv_*2, wv_*2+1}; B = rel_q[h] (4 rt frags)
        s16x8 qb0[4], qb1[4];
        #pragma unroll
        for (int rt = 0; rt < 4; ++rt) {
            const float* Rp = RelQ + ((size_t)h * NR + rt * 16 + lr) * NDK + kg * 8;
            qb0[rt] = loadcvt8(Rp);
            qb1[rt] = loadcvt8(Rp + 32);
        }
        #pragma unroll
        for (int mi = 0; mi < 2; ++mi) {
            const int mt = wv_ * 2 + mi;
            const u16* Kp = kbf + ((size_t)bh * NL + mt * 16 + lr) * 64 + kg * 8;
            s16x8 ka0 = *(const s16x8*)Kp;
            s16x8 ka1 = *(const s16x8*)(Kp + 32);
            #pragma unroll
            for (int rt = 0; rt < 4; ++rt) {
                f32x4 acc = {0.f, 0.f, 0.f, 0.f};
                acc = __builtin_amdgcn_mfma_f32_16x16x32_bf16(ka0, qb0[rt], acc, 0, 0, 0);
                acc = __builtin_amdgcn_mfma_f32_16x16x32_bf16(ka1, qb1[rt], acc, 0, 0, 0);
                #pragma unroll
                for (int r = 0; r < 4; ++r)
                    psall[mt * 16 + kg * 4 + r][rt * 16 + lr] = f2bf(acc[r]);
            }
        }
    }
    __syncthreads();

    // ---- Phase B: gathers + scale + mask (no barriers) ----
    const int i  = t >> 5;        // row 0..15
    const int jj = t & 31;        // lane 0..31
    {
        const size_t rowbase = ((size_t)b * NL + l0 + i) * NL;
        #pragma unroll
        for (int s = 0; s < 8; ++s) {
            const int m = s * 32 + jj;
            int r = RelPos[rowbase + m];
            float val = sc[i][m] + cs[i][r] + bf2f(psall[m][r]);
            val *= (1.0f / 24.0f);   // 1 / (3 * sqrt(64))
            if (maskv[m] != 0.0f) val = -1e9f;
            sc[i][m] = val;          // same thread re-reads in phase C
        }
    }

    // ---- Phase C: softmax, row i by its 32 lanes (no barriers) ----
    {
        float mx = -INFINITY;
        #pragma unroll
        for (int s = 0; s < 8; ++s) mx = fmaxf(mx, sc[i][jj + 32*s]);
        #pragma unroll
        for (int off = 16; off >= 1; off >>= 1) mx = fmaxf(mx, __shfl_xor(mx, off, 32));

        float sum = 0.f;
        float ev[8];
        #pragma unroll
        for (int s = 0; s < 8; ++s) {
            ev[s] = __expf(sc[i][jj + 32*s] - mx);
            sum += ev[s];
        }
        #pragma unroll
        for (int off = 16; off >= 1; off >>= 1) sum += __shfl_xor(sum, off, 32);
        float inv = 1.0f / sum;
        #pragma unroll
        for (int s = 0; s < 8; ++s) sc[i][jj + 32*s] = ev[s] * inv;
    }
    __syncthreads();

    // ---- Phase D: stream rel_v slice (nontemporal) fused with p@V ----
    {
        const int half = t >> 8;        // m parity
        const int di   = (t >> 4) & 15; // row 0..15
        const int d4   = t & 15;        // f32x4 column 0..15

        const float* rvp = RV + (((size_t)(b * NL + l0 + di)) * NL) * ND + h * 64 + d4 * 4;
        const float* vvp = vws + ((size_t)bh * NL) * 64 + d4 * 4;

        f32x4 acc = {0.f, 0.f, 0.f, 0.f};
        #pragma unroll 4
        for (int m = half; m < NL; m += 2) {
            float w  = sc[di][m];
            f32x4 rv = __builtin_nontemporal_load((const f32x4*)(rvp + (size_t)m * ND));
            f32x4 vv = *(const f32x4*)(vvp + (size_t)m * 64);
            acc += w * (rv + vv);
        }

        if (half) redv[t & 255] = acc;
        __syncthreads();
        if (!half) {
            acc += redv[t];
            u16x4 o;
            o.x = f2bf(acc.x); o.y = f2bf(acc.y); o.z = f2bf(acc.z); o.w = f2bf(acc.w);
            *(u16x4*)&CTXB[((size_t)(b * NL + l0 + di)) * ND + h * 64 + d4 * 4] = o;
        }
    }
}

// ---------------------------------------------------------------------------
// Kernel 3: out = ctx @ Wo^T + bo via MFMA.  16x64 tiles, grid (64,8)=512
// blocks = 2/CU.  Wave w owns col-tile w*16; Wo f32 cvt'd on the fly.
// ---------------------------------------------------------------------------
__global__ __launch_bounds__(256)
void out_proj_mfma_kernel(const u16* __restrict__ A, const float* __restrict__ Wo,
                          const float* __restrict__ bias, float* __restrict__ C)
{
    const int t    = threadIdx.x;
    const int wv_  = t >> 6;
    const int lane = t & 63;
    const int lr   = lane & 15;
    const int kg   = lane >> 4;

    const int m0 = blockIdx.x * 16;
    const int n0 = blockIdx.y * 64 + wv_ * 16;

    const u16*   Ap = A  + (size_t)(m0 + lr) * ND + kg * 8;
    const float* Bp = Wo + (size_t)(n0 + lr) * ND + kg * 8;

    f32x4 acc = {0.f, 0.f, 0.f, 0.f};

    for (int kt = 0; kt < 16; ++kt) {
        s16x8 a = *(const s16x8*)(Ap + kt * 32);
        s16x8 b = loadcvt8(Bp + kt * 32);
        acc = __builtin_amdgcn_mfma_f32_16x16x32_bf16(a, b, acc, 0, 0, 0);
    }

    const int col = n0 + lr;
    const float bb = bias[col];
    #pragma unroll
    for (int r = 0; r < 4; ++r) {
        int row = m0 + kg * 4 + r;
        C[(size_t)row * ND + col] = acc[r] + bb;
    }
}

// ---------------------------------------------------------------------------
extern "C" void kernel_launch(void* const* d_in, const int* in_sizes, int n_in,
                              void* d_out, int out_size, void* d_ws, size_t ws_size,
                              hipStream_t stream)
{
    const float* query   = (const float*)d_in[0];
    const float* key     = (const float*)d_in[1];
    const float* value   = (const float*)d_in[2];
    const void*  mask    = d_in[3];
    const int*   rel_pos = (const int*)d_in[4];
    const float* rel_q   = (const float*)d_in[5];
    const float* rel_k   = (const float*)d_in[6];
    const float* rel_v   = (const float*)d_in[7];
    const float* Wq = (const float*)d_in[8];
    const float* bq = (const float*)d_in[9];
    const float* Wk = (const float*)d_in[10];
    const float* bk = (const float*)d_in[11];
    const float* Wv = (const float*)d_in[12];
    const float* bv = (const float*)d_in[13];
    const float* Wo = (const float*)d_in[14];
    const float* bo = (const float*)d_in[15];

    // ---- workspace layout ----
    float* vws  = (float*)d_ws;           // 524288 f32 [B,H,L,64]
    u16* qbf  = (u16*)(vws + 524288);     // 524288 u16 [B,H,L,64]
    u16* kbf  = qbf + 524288;             // 524288 u16
    u16* ctxb = kbf + 524288;             // 524288 u16 [B*L, 512]

    gemm3_mfma_kernel<<<dim3(32, 8, 3), 256, 0, stream>>>(
        query, key, value, Wq, bq, Wk, bk, Wv, bv, qbf, kbf, vws);

    attn_fused_kernel<<<dim3(512), 512, 0, stream>>>(
        qbf, kbf, vws, rel_k, rel_q, rel_pos, mask, rel_v, ctxb);

    out_proj_mfma_kernel<<<dim3(64, 8), 256, 0, stream>>>(
        ctxb, Wo, bo, (float*)d_out);
}